// Round 23
// baseline (53.933 us; speedup 1.0000x reference)
//
#include <hip/hip_runtime.h>

#define NN 1024
#define HH 128
#define CC 7
#define BI 8            // i per block (4 waves x 2)
#define BJ 64           // j per chunk
#define NCH 4           // 16-j MFMA chunks per j-chunk
#define QPADU 68        // dwords per qpk row (64 + 4 pad): 2-way-only bank alias

typedef __attribute__((ext_vector_type(8))) short bf16x8;
typedef __attribute__((ext_vector_type(4))) float f32x4;

__device__ inline unsigned f2bf(float x) {
    union { float f; unsigned u; } v; v.f = x;
    return (v.u + 0x7FFFu + ((v.u >> 16) & 1u)) >> 16;     // RNE, low 16
}
__device__ inline unsigned bfrnd(unsigned u) {             // RNE, keep high 16
    return u + 0x7FFFu + ((u >> 16) & 1u);
}
__device__ inline float bitsf(unsigned u) {
    union { unsigned u; float f; } v; v.u = u; return v.f;
}

// ---- Kernel A: P = e@mW1[0:H] + mb1 ; Qpk packed bf16 ; zero HS ------------
__global__ __launch_bounds__(256) void precompute_pq(
    const float* __restrict__ e, const float* __restrict__ mW1,
    const float* __restrict__ mb1, float* __restrict__ P,
    unsigned* __restrict__ Qpk, float* __restrict__ HS)
{
    const int row = blockIdx.x;
    const int t   = threadIdx.x;
    const int s   = t >> 7;
    const int h   = t & 127;
    __shared__ float eL[HH];
    __shared__ float part[2][2][HH];
    __shared__ float qs[HH];
    if (s == 0) eL[h] = e[(size_t)row * HH + h];
    else        HS[(size_t)row * HH + h] = 0.f;   // zero accumulator buffer
    __syncthreads();
    float p = 0.f, q = 0.f;
    const int k0 = s * 64;
    for (int k = k0; k < k0 + 64; ++k) {
        const float ev = eL[k];
        p = fmaf(ev, mW1[k * HH + h], p);
        q = fmaf(ev, mW1[(HH + k) * HH + h], q);
    }
    part[s][0][h] = p; part[s][1][h] = q;
    __syncthreads();
    if (s == 0) P[(size_t)row * HH + h] = part[0][0][h] + part[1][0][h] + mb1[h];
    else        qs[h] = part[0][1][h] + part[1][1][h];
    __syncthreads();
    if (t < 64) {
        const unsigned lo = f2bf(qs[t]);
        const unsigned hi = f2bf(qs[t + 64]);
        Qpk[(size_t)row * 64 + t] = lo | (hi << 16);
    }
}

// ---- Kernel B: MFMA message+reduce — 2 j-chunks per block, atomic HS -------
// HS[i,h] += sum_j relu( (c[i,j,:]@Cw)[h] + P[i,h] + Q[j,h] )
// MFMA 16x16x32 bf16; A lane l: m=l&15, k=(l>>4)*8+e (lanes>=16 garbage x B=0);
// C/D lane l reg r: row=(l>>4)*4+r (j), col=l&15 (h)   [m89-verified]
__global__ __launch_bounds__(256, 5) void msg_mfma(
    const float* __restrict__ c, const float* __restrict__ mW1,
    const float* __restrict__ P, const unsigned* __restrict__ Qpk,
    float* __restrict__ HS)
{
    const int bid   = blockIdx.x;
    const int islab = bid >> 3;            // 0..127
    const int spair = bid & 7;             // 0..7 -> slices 2*spair, 2*spair+1
    const int i0    = islab * BI;
    const int t     = threadIdx.x;
    const int w     = t >> 6;              // wave 0..3
    const int l     = t & 63;
    const int g     = l >> 4;              // lane group 0..3
    const int col   = l & 15;
    const int iw0   = i0 + 2 * w;

    __shared__ unsigned qpk[BJ * QPADU];   // 17408 B
    __shared__ uint4 abuf[BI * BJ];        // 8192 B
    __shared__ uint4 bld[129];             // 2064 B (slot 128 = zeros)
    __shared__ float pld[BI * HH];         // 4096 B -> 31760 B total

    // ---- stage Cw -> bld (threads 0..127); slot 128 zeroed  (once per block)
    if (t < 128) {
        const int ht = t >> 4;
        const int cl = t & 15;
        const float* __restrict__ wp = mW1 + (2 * HH) * HH + 16 * ht + cl;
        uint4 bv;
        bv.x = f2bf(wp[0])      | (f2bf(wp[HH])     << 16);
        bv.y = f2bf(wp[2 * HH]) | (f2bf(wp[3 * HH]) << 16);
        bv.z = f2bf(wp[4 * HH]) | (f2bf(wp[5 * HH]) << 16);
        bv.w = f2bf(wp[6 * HH]);           // k=7 zero
        bld[t] = bv;
    } else if (t == 128) {
        bld[128] = (uint4){0u, 0u, 0u, 0u};
    }
    // ---- stage P block (8 i x 128 h)  (once per block)
    #pragma unroll
    for (int rep = 0; rep < 4; ++rep) {
        const int idx = t + rep * 256;     // 0..1023
        pld[idx] = P[(size_t)i0 * HH + idx];
    }

    float acc[2][8];
    #pragma unroll
    for (int ii = 0; ii < 2; ++ii)
        #pragma unroll
        for (int ht = 0; ht < 8; ++ht) acc[ii][ht] = 0.f;

    const int pbase0 = (2 * w + 0) * HH + col;
    const int pbase1 = (2 * w + 1) * HH + col;

    #pragma unroll 1
    for (int jc = 0; jc < 2; ++jc) {
        const int j0b = spair * 128 + jc * BJ;
        if (jc > 0) __syncthreads();       // all waves done reading prev chunk
        // ---- stage Qpk tile (pure u32 copy, coalesced)
        #pragma unroll
        for (int rep = 0; rep < 4; ++rep) {
            const int idx = t + rep * 256; // uint4 units, 0..1023
            const int row = idx >> 4;
            const int c4  = (idx & 15) * 4;
            *(uint4*)(qpk + row * QPADU + c4) =
                *(const uint4*)(Qpk + (size_t)(j0b + row) * 64 + c4);
        }
        // ---- stage c -> abuf as packed bf16x8 rows (coalesced)
        #pragma unroll
        for (int rep = 0; rep < 2; ++rep) {
            const int rr = t + rep * 256;  // 0..511
            const int ii = rr >> 6;
            const int jj = rr & 63;
            const unsigned* __restrict__ cp = (const unsigned*)
                (c + ((size_t)(i0 + ii) * NN + j0b + jj) * CC);
            unsigned d0 = bfrnd(cp[0]), d1 = bfrnd(cp[1]), d2 = bfrnd(cp[2]);
            unsigned d3 = bfrnd(cp[3]), d4 = bfrnd(cp[4]), d5 = bfrnd(cp[5]);
            unsigned d6 = bfrnd(cp[6]);
            uint4 pk;
            pk.x = __builtin_amdgcn_perm(d1, d0, 0x07060302u);
            pk.y = __builtin_amdgcn_perm(d3, d2, 0x07060302u);
            pk.z = __builtin_amdgcn_perm(d5, d4, 0x07060302u);
            pk.w = d6 >> 16;               // k=7 pad zero
            abuf[rr] = pk;
        }
        __syncthreads();                   // staging done; LDS read-only now

        // ---- hoist A-fragments into registers
        bf16x8 af[2][NCH];
        #pragma unroll
        for (int ch = 0; ch < NCH; ++ch) {
            af[0][ch] = __builtin_bit_cast(bf16x8, abuf[(2 * w + 0) * 64 + ch * 16 + col]);
            af[1][ch] = __builtin_bit_cast(bf16x8, abuf[(2 * w + 1) * 64 + ch * 16 + col]);
        }

        #pragma unroll 1
        for (int hp = 0; hp < 4; ++hp) {
            const int bi_lo = (g == 0) ? (hp * 16 + col) : 128;
            const int bi_hi = (g == 0) ? ((hp + 4) * 16 + col) : 128;
            const bf16x8 blo = __builtin_bit_cast(bf16x8, bld[bi_lo]);
            const bf16x8 bhi = __builtin_bit_cast(bf16x8, bld[bi_hi]);
            const float pv0lo = pld[pbase0 + 16 * hp];
            const float pv1lo = pld[pbase1 + 16 * hp];
            const float pv0hi = pld[pbase0 + 16 * (hp + 4)];
            const float pv1hi = pld[pbase1 + 16 * (hp + 4)];
            #pragma unroll
            for (int ch = 0; ch < NCH; ++ch) {
                unsigned u[4];
                #pragma unroll
                for (int r = 0; r < 4; ++r)
                    u[r] = qpk[(ch * 16 + g * 4 + r) * QPADU + 16 * hp + col];
                {   // lo half: ht = hp
                    f32x4 d0, d1;
                    #pragma unroll
                    for (int r = 0; r < 4; ++r) {
                        const float fa = bitsf(u[r] << 16);
                        d0[r] = pv0lo + fa;
                        d1[r] = pv1lo + fa;
                    }
                    d0 = __builtin_amdgcn_mfma_f32_16x16x32_bf16(af[0][ch], blo, d0, 0, 0, 0);
                    d1 = __builtin_amdgcn_mfma_f32_16x16x32_bf16(af[1][ch], blo, d1, 0, 0, 0);
                    #pragma unroll
                    for (int r = 0; r < 4; ++r) {
                        acc[0][hp] += fmaxf(d0[r], 0.f);
                        acc[1][hp] += fmaxf(d1[r], 0.f);
                    }
                }
                {   // hi half: ht = hp + 4
                    f32x4 d0, d1;
                    #pragma unroll
                    for (int r = 0; r < 4; ++r) {
                        const float fb = bitsf(u[r] & 0xFFFF0000u);
                        d0[r] = pv0hi + fb;
                        d1[r] = pv1hi + fb;
                    }
                    d0 = __builtin_amdgcn_mfma_f32_16x16x32_bf16(af[0][ch], bhi, d0, 0, 0, 0);
                    d1 = __builtin_amdgcn_mfma_f32_16x16x32_bf16(af[1][ch], bhi, d1, 0, 0, 0);
                    #pragma unroll
                    for (int r = 0; r < 4; ++r) {
                        acc[0][hp + 4] += fmaxf(d0[r], 0.f);
                        acc[1][hp + 4] += fmaxf(d1[r], 0.f);
                    }
                }
            }
        }
    }

    // reduce partial j-sums across the 4 lane groups (once per block)
    #pragma unroll
    for (int ii = 0; ii < 2; ++ii)
        #pragma unroll
        for (int ht = 0; ht < 8; ++ht) {
            float a = acc[ii][ht];
            a += __shfl_xor(a, 16, 64);
            a += __shfl_xor(a, 32, 64);
            acc[ii][ht] = a;
        }
    // accumulate: group g adds ht = g and g+4 into HS (device-scope atomic)
    #pragma unroll
    for (int ii = 0; ii < 2; ++ii)
        #pragma unroll
        for (int s = 0; s < 2; ++s) {
            const int ht = g + 4 * s;
            atomicAdd(&HS[(size_t)(iw0 + ii) * HH + 16 * ht + col], acc[ii][ht]);
        }
}

// ---- Kernel C: agg -> u -> out, k-split across thread halves ---------------
__global__ __launch_bounds__(256) void final_mlp(
    const float* __restrict__ e, const float* __restrict__ HS,
    const float* __restrict__ mW2, const float* __restrict__ mb2,
    const float* __restrict__ uW1, const float* __restrict__ ub1,
    const float* __restrict__ uW2, const float* __restrict__ ub2,
    float* __restrict__ out)
{
    const int t  = threadIdx.x;
    const int s  = t >> 7;
    const int h  = t & 127;
    const int i0 = blockIdx.x * 2;
    __shared__ float hsL[2][HH], eL[2][HH], aggL[2][HH], t1L[2][HH], part[2][2][HH];

    {
        const size_t ih = (size_t)(i0 + s) * HH + h;
        hsL[s][h] = HS[ih];               // single load (atomic-accumulated)
        eL[s][h]  = e[ih];
    }
    __syncthreads();

    {   // stage 1: agg = HS@mW2 + N*mb2   (k-half split)
        float a0 = 0.f, a1 = 0.f;
        const int k0 = 64 * s;
        for (int k = k0; k < k0 + 64; ++k) {
            const float wv = mW2[k * HH + h];
            a0 = fmaf(hsL[0][k], wv, a0);
            a1 = fmaf(hsL[1][k], wv, a1);
        }
        part[s][0][h] = a0; part[s][1][h] = a1;
    }
    __syncthreads();
    aggL[s][h] = part[0][s][h] + part[1][s][h] + (float)NN * mb2[h];
    __syncthreads();

    {   // stage 2: t1 = relu([agg,e]@uW1 + ub1)
        float b0 = 0.f, b1 = 0.f;
        const float* __restrict__ src   = (s == 0) ? &aggL[0][0] : &eL[0][0];
        const float* __restrict__ wbase = uW1 + (size_t)s * HH * HH;
        for (int k = 0; k < HH; ++k) {
            const float wv = wbase[k * HH + h];
            b0 = fmaf(src[k],      wv, b0);
            b1 = fmaf(src[HH + k], wv, b1);
        }
        part[s][0][h] = b0; part[s][1][h] = b1;
    }
    __syncthreads();
    t1L[s][h] = fmaxf(part[0][s][h] + part[1][s][h] + ub1[h], 0.f);
    __syncthreads();

    {   // stage 3: out = t1@uW2 + ub2
        float c0 = 0.f, c1 = 0.f;
        const int k0 = 64 * s;
        for (int k = k0; k < k0 + 64; ++k) {
            const float wv = uW2[k * HH + h];
            c0 = fmaf(t1L[0][k], wv, c0);
            c1 = fmaf(t1L[1][k], wv, c1);
        }
        part[s][0][h] = c0; part[s][1][h] = c1;
    }
    __syncthreads();
    out[(size_t)(i0 + s) * HH + h] = part[0][s][h] + part[1][s][h] + ub2[h];
}

extern "C" void kernel_launch(void* const* d_in, const int* in_sizes, int n_in,
                              void* d_out, int out_size, void* d_ws, size_t ws_size,
                              hipStream_t stream) {
    const float* e   = (const float*)d_in[0];
    const float* c   = (const float*)d_in[1];
    const float* mW1 = (const float*)d_in[2];
    const float* mb1 = (const float*)d_in[3];
    const float* mW2 = (const float*)d_in[4];
    const float* mb2 = (const float*)d_in[5];
    const float* uW1 = (const float*)d_in[6];
    const float* ub1 = (const float*)d_in[7];
    const float* uW2 = (const float*)d_in[8];
    const float* ub2 = (const float*)d_in[9];
    float* out = (float*)d_out;

    float*    P   = (float*)d_ws;                 // N*H f32
    unsigned* Qpk = (unsigned*)(P + NN * HH);     // N*64 u32 (packed bf16 pairs)
    float*    HS  = (float*)(Qpk + NN * 64);      // N*H f32 accumulator

    precompute_pq<<<NN, 256, 0, stream>>>(e, mW1, mb1, P, Qpk, HS);
    msg_mfma<<<(NN / BI) * 8, 256, 0, stream>>>(c, mW1, P, Qpk, HS);
    final_mlp<<<NN / 2, 256, 0, stream>>>(e, HS, mW2, mb2, uW1, ub1, uW2, ub2, out);
}

// Round 24
// 45.728 us; speedup vs baseline: 1.1794x; 1.1794x over previous
//
#include <hip/hip_runtime.h>

#define NN 1024
#define HH 128
#define CC 7
#define BI 8            // i per block (4 waves x 2)
#define BJ 64           // j per block
#define NCH 4           // 16-j MFMA chunks
#define NSLICE 16       // j-slices (grid dim; partials atomic into HS)
#define QPADU 68        // dwords per qpk row (64 + 4 pad): 2-way-only bank alias

typedef __attribute__((ext_vector_type(8))) short bf16x8;
typedef __attribute__((ext_vector_type(4))) float f32x4;

__device__ inline unsigned f2bf(float x) {
    union { float f; unsigned u; } v; v.f = x;
    return (v.u + 0x7FFFu + ((v.u >> 16) & 1u)) >> 16;     // RNE, low 16
}
__device__ inline unsigned bfrnd(unsigned u) {             // RNE, keep high 16
    return u + 0x7FFFu + ((u >> 16) & 1u);
}
__device__ inline float bitsf(unsigned u) {
    union { unsigned u; float f; } v; v.u = u; return v.f;
}

// ---- Kernel A: P = e@mW1[0:H] + mb1 ; Qpk packed bf16 ; zero HS ------------
__global__ __launch_bounds__(256) void precompute_pq(
    const float* __restrict__ e, const float* __restrict__ mW1,
    const float* __restrict__ mb1, float* __restrict__ P,
    unsigned* __restrict__ Qpk, float* __restrict__ HS)
{
    const int row = blockIdx.x;
    const int t   = threadIdx.x;
    const int s   = t >> 7;
    const int h   = t & 127;
    __shared__ float eL[HH];
    __shared__ float part[2][2][HH];
    __shared__ float qs[HH];
    if (s == 0) eL[h] = e[(size_t)row * HH + h];
    else        HS[(size_t)row * HH + h] = 0.f;   // zero accumulator buffer
    __syncthreads();
    float p = 0.f, q = 0.f;
    const int k0 = s * 64;
    for (int k = k0; k < k0 + 64; ++k) {
        const float ev = eL[k];
        p = fmaf(ev, mW1[k * HH + h], p);
        q = fmaf(ev, mW1[(HH + k) * HH + h], q);
    }
    part[s][0][h] = p; part[s][1][h] = q;
    __syncthreads();
    if (s == 0) P[(size_t)row * HH + h] = part[0][0][h] + part[1][0][h] + mb1[h];
    else        qs[h] = part[0][1][h] + part[1][1][h];
    __syncthreads();
    if (t < 64) {
        const unsigned lo = f2bf(qs[t]);
        const unsigned hi = f2bf(qs[t + 64]);
        Qpk[(size_t)row * 64 + t] = lo | (hi << 16);
    }
}

// ---- Kernel B: MFMA message+reduce — atomic HS accumulate (R22 best) -------
// HS[i,h] += sum_{j in slice} relu( (c[i,j,:]@Cw)[h] + P[i,h] + Q[j,h] )
// MFMA 16x16x32 bf16; A lane l: m=l&15, k=(l>>4)*8+e (lanes>=16 garbage x B=0);
// C/D lane l reg r: row=(l>>4)*4+r (j), col=l&15 (h)   [m89-verified]
__global__ __launch_bounds__(256, 5) void msg_mfma(
    const float* __restrict__ c, const float* __restrict__ mW1,
    const float* __restrict__ P, const unsigned* __restrict__ Qpk,
    float* __restrict__ HS)
{
    const int bid   = blockIdx.x;
    const int islab = bid >> 4;            // 0..127
    const int slice = bid & 15;            // 0..15
    const int i0    = islab * BI;
    const int j0b   = slice * BJ;
    const int t     = threadIdx.x;
    const int w     = t >> 6;              // wave 0..3
    const int l     = t & 63;
    const int g     = l >> 4;              // lane group 0..3
    const int col   = l & 15;
    const int iw0   = i0 + 2 * w;

    __shared__ unsigned qpk[BJ * QPADU];   // 17408 B
    __shared__ uint4 abuf[BI * BJ];        // 8192 B
    __shared__ uint4 bld[129];             // 2064 B (slot 128 = zeros)
    __shared__ float pld[BI * HH];         // 4096 B -> 31760 B total (5 blk/CU)

    // ---- stage Qpk tile (pure u32 copy, coalesced)
    #pragma unroll
    for (int rep = 0; rep < 4; ++rep) {
        const int idx = t + rep * 256;     // uint4 units, 0..1023
        const int row = idx >> 4;
        const int c4  = (idx & 15) * 4;
        *(uint4*)(qpk + row * QPADU + c4) =
            *(const uint4*)(Qpk + (size_t)(j0b + row) * 64 + c4);
    }
    // ---- stage c -> abuf as packed bf16x8 rows (coalesced)
    #pragma unroll
    for (int rep = 0; rep < 2; ++rep) {
        const int rr = t + rep * 256;      // 0..511
        const int ii = rr >> 6;
        const int jj = rr & 63;
        const unsigned* __restrict__ cp = (const unsigned*)
            (c + ((size_t)(i0 + ii) * NN + j0b + jj) * CC);
        unsigned d0 = bfrnd(cp[0]), d1 = bfrnd(cp[1]), d2 = bfrnd(cp[2]);
        unsigned d3 = bfrnd(cp[3]), d4 = bfrnd(cp[4]), d5 = bfrnd(cp[5]);
        unsigned d6 = bfrnd(cp[6]);
        uint4 pk;
        pk.x = __builtin_amdgcn_perm(d1, d0, 0x07060302u);
        pk.y = __builtin_amdgcn_perm(d3, d2, 0x07060302u);
        pk.z = __builtin_amdgcn_perm(d5, d4, 0x07060302u);
        pk.w = d6 >> 16;                   // k=7 pad zero
        abuf[rr] = pk;
    }
    // ---- stage Cw -> bld (threads 0..127); slot 128 zeroed
    if (t < 128) {
        const int ht = t >> 4;
        const int cl = t & 15;
        const float* __restrict__ wp = mW1 + (2 * HH) * HH + 16 * ht + cl;
        uint4 bv;
        bv.x = f2bf(wp[0])      | (f2bf(wp[HH])     << 16);
        bv.y = f2bf(wp[2 * HH]) | (f2bf(wp[3 * HH]) << 16);
        bv.z = f2bf(wp[4 * HH]) | (f2bf(wp[5 * HH]) << 16);
        bv.w = f2bf(wp[6 * HH]);           // k=7 zero
        bld[t] = bv;
    } else if (t == 128) {
        bld[128] = (uint4){0u, 0u, 0u, 0u};
    }
    // ---- stage P block (8 i x 128 h)
    #pragma unroll
    for (int rep = 0; rep < 4; ++rep) {
        const int idx = t + rep * 256;     // 0..1023
        pld[idx] = P[(size_t)i0 * HH + idx];
    }

    float acc[2][8];
    #pragma unroll
    for (int ii = 0; ii < 2; ++ii)
        #pragma unroll
        for (int ht = 0; ht < 8; ++ht) acc[ii][ht] = 0.f;

    __syncthreads();                       // staging done; LDS read-only after

    // ---- hoist A-fragments into registers ONCE
    bf16x8 af[2][NCH];
    #pragma unroll
    for (int ch = 0; ch < NCH; ++ch) {
        af[0][ch] = __builtin_bit_cast(bf16x8, abuf[(2 * w + 0) * 64 + ch * 16 + col]);
        af[1][ch] = __builtin_bit_cast(bf16x8, abuf[(2 * w + 1) * 64 + ch * 16 + col]);
    }

    const int pbase0 = (2 * w + 0) * HH + col;
    const int pbase1 = (2 * w + 1) * HH + col;

    #pragma unroll 1
    for (int hp = 0; hp < 4; ++hp) {
        const int bi_lo = (g == 0) ? (hp * 16 + col) : 128;
        const int bi_hi = (g == 0) ? ((hp + 4) * 16 + col) : 128;
        const bf16x8 blo = __builtin_bit_cast(bf16x8, bld[bi_lo]);
        const bf16x8 bhi = __builtin_bit_cast(bf16x8, bld[bi_hi]);
        const float pv0lo = pld[pbase0 + 16 * hp];
        const float pv1lo = pld[pbase1 + 16 * hp];
        const float pv0hi = pld[pbase0 + 16 * (hp + 4)];
        const float pv1hi = pld[pbase1 + 16 * (hp + 4)];
        #pragma unroll
        for (int ch = 0; ch < NCH; ++ch) {
            unsigned u[4];
            #pragma unroll
            for (int r = 0; r < 4; ++r)
                u[r] = qpk[(ch * 16 + g * 4 + r) * QPADU + 16 * hp + col];
            {   // lo half: ht = hp
                f32x4 d0, d1;
                #pragma unroll
                for (int r = 0; r < 4; ++r) {
                    const float fa = bitsf(u[r] << 16);
                    d0[r] = pv0lo + fa;
                    d1[r] = pv1lo + fa;
                }
                d0 = __builtin_amdgcn_mfma_f32_16x16x32_bf16(af[0][ch], blo, d0, 0, 0, 0);
                d1 = __builtin_amdgcn_mfma_f32_16x16x32_bf16(af[1][ch], blo, d1, 0, 0, 0);
                #pragma unroll
                for (int r = 0; r < 4; ++r) {
                    acc[0][hp] += fmaxf(d0[r], 0.f);
                    acc[1][hp] += fmaxf(d1[r], 0.f);
                }
            }
            {   // hi half: ht = hp + 4
                f32x4 d0, d1;
                #pragma unroll
                for (int r = 0; r < 4; ++r) {
                    const float fb = bitsf(u[r] & 0xFFFF0000u);
                    d0[r] = pv0hi + fb;
                    d1[r] = pv1hi + fb;
                }
                d0 = __builtin_amdgcn_mfma_f32_16x16x32_bf16(af[0][ch], bhi, d0, 0, 0, 0);
                d1 = __builtin_amdgcn_mfma_f32_16x16x32_bf16(af[1][ch], bhi, d1, 0, 0, 0);
                #pragma unroll
                for (int r = 0; r < 4; ++r) {
                    acc[0][hp + 4] += fmaxf(d0[r], 0.f);
                    acc[1][hp + 4] += fmaxf(d1[r], 0.f);
                }
            }
        }
    }

    // reduce partial j-sums across the 4 lane groups
    #pragma unroll
    for (int ii = 0; ii < 2; ++ii)
        #pragma unroll
        for (int ht = 0; ht < 8; ++ht) {
            float a = acc[ii][ht];
            a += __shfl_xor(a, 16, 64);
            a += __shfl_xor(a, 32, 64);
            acc[ii][ht] = a;
        }
    // accumulate: group g adds ht = g and g+4 into HS (device-scope atomic)
    #pragma unroll
    for (int ii = 0; ii < 2; ++ii)
        #pragma unroll
        for (int s = 0; s < 2; ++s) {
            const int ht = g + 4 * s;
            atomicAdd(&HS[(size_t)(iw0 + ii) * HH + 16 * ht + col], acc[ii][ht]);
        }
}

// ---- Kernel C: agg -> u -> out, k-split across thread halves ---------------
__global__ __launch_bounds__(256) void final_mlp(
    const float* __restrict__ e, const float* __restrict__ HS,
    const float* __restrict__ mW2, const float* __restrict__ mb2,
    const float* __restrict__ uW1, const float* __restrict__ ub1,
    const float* __restrict__ uW2, const float* __restrict__ ub2,
    float* __restrict__ out)
{
    const int t  = threadIdx.x;
    const int s  = t >> 7;
    const int h  = t & 127;
    const int i0 = blockIdx.x * 2;
    __shared__ float hsL[2][HH], eL[2][HH], aggL[2][HH], t1L[2][HH], part[2][2][HH];

    {
        const size_t ih = (size_t)(i0 + s) * HH + h;
        hsL[s][h] = HS[ih];               // single load (atomic-accumulated)
        eL[s][h]  = e[ih];
    }
    __syncthreads();

    {   // stage 1: agg = HS@mW2 + N*mb2   (k-half split)
        float a0 = 0.f, a1 = 0.f;
        const int k0 = 64 * s;
        for (int k = k0; k < k0 + 64; ++k) {
            const float wv = mW2[k * HH + h];
            a0 = fmaf(hsL[0][k], wv, a0);
            a1 = fmaf(hsL[1][k], wv, a1);
        }
        part[s][0][h] = a0; part[s][1][h] = a1;
    }
    __syncthreads();
    aggL[s][h] = part[0][s][h] + part[1][s][h] + (float)NN * mb2[h];
    __syncthreads();

    {   // stage 2: t1 = relu([agg,e]@uW1 + ub1)
        float b0 = 0.f, b1 = 0.f;
        const float* __restrict__ src   = (s == 0) ? &aggL[0][0] : &eL[0][0];
        const float* __restrict__ wbase = uW1 + (size_t)s * HH * HH;
        for (int k = 0; k < HH; ++k) {
            const float wv = wbase[k * HH + h];
            b0 = fmaf(src[k],      wv, b0);
            b1 = fmaf(src[HH + k], wv, b1);
        }
        part[s][0][h] = b0; part[s][1][h] = b1;
    }
    __syncthreads();
    t1L[s][h] = fmaxf(part[0][s][h] + part[1][s][h] + ub1[h], 0.f);
    __syncthreads();

    {   // stage 3: out = t1@uW2 + ub2
        float c0 = 0.f, c1 = 0.f;
        const int k0 = 64 * s;
        for (int k = k0; k < k0 + 64; ++k) {
            const float wv = uW2[k * HH + h];
            c0 = fmaf(t1L[0][k], wv, c0);
            c1 = fmaf(t1L[1][k], wv, c1);
        }
        part[s][0][h] = c0; part[s][1][h] = c1;
    }
    __syncthreads();
    out[(size_t)(i0 + s) * HH + h] = part[0][s][h] + part[1][s][h] + ub2[h];
}

extern "C" void kernel_launch(void* const* d_in, const int* in_sizes, int n_in,
                              void* d_out, int out_size, void* d_ws, size_t ws_size,
                              hipStream_t stream) {
    const float* e   = (const float*)d_in[0];
    const float* c   = (const float*)d_in[1];
    const float* mW1 = (const float*)d_in[2];
    const float* mb1 = (const float*)d_in[3];
    const float* mW2 = (const float*)d_in[4];
    const float* mb2 = (const float*)d_in[5];
    const float* uW1 = (const float*)d_in[6];
    const float* ub1 = (const float*)d_in[7];
    const float* uW2 = (const float*)d_in[8];
    const float* ub2 = (const float*)d_in[9];
    float* out = (float*)d_out;

    float*    P   = (float*)d_ws;                 // N*H f32
    unsigned* Qpk = (unsigned*)(P + NN * HH);     // N*64 u32 (packed bf16 pairs)
    float*    HS  = (float*)(Qpk + NN * 64);      // N*H f32 accumulator

    precompute_pq<<<NN, 256, 0, stream>>>(e, mW1, mb1, P, Qpk, HS);
    msg_mfma<<<(NN / BI) * NSLICE, 256, 0, stream>>>(c, mW1, P, Qpk, HS);
    final_mlp<<<NN / 2, 256, 0, stream>>>(e, HS, mW2, mb2, uW1, ub1, uW2, ub2, out);
}